// Round 1
// baseline (682.657 us; speedup 1.0000x reference)
//
#include <hip/hip_runtime.h>

#define IN_DIM 64
#define H 8
#define D 16
#define HD 128
#define CLAMP_V 5.0f
#define ECHUNK 8

// ---------------- QKV projection: one block per node ----------------
__global__ void __launch_bounds__(128) qkv_kernel(
    const float* __restrict__ x,
    const float* __restrict__ Qw, const float* __restrict__ Qb,
    const float* __restrict__ Kw, const float* __restrict__ Kb,
    const float* __restrict__ Vw, const float* __restrict__ Vb,
    float* __restrict__ Q, float* __restrict__ K, float* __restrict__ V)
{
    const int n = blockIdx.x;
    const int t = threadIdx.x;
    __shared__ float xs[IN_DIM];
    if (t < IN_DIM) xs[t] = x[n * IN_DIM + t];
    __syncthreads();
    float aq = Qb[t], ak = Kb[t], av = Vb[t];
#pragma unroll 8
    for (int k = 0; k < IN_DIM; ++k) {
        const float xv = xs[k];
        aq = fmaf(xv, Qw[k * HD + t], aq);
        ak = fmaf(xv, Kw[k * HD + t], ak);
        av = fmaf(xv, Vw[k * HD + t], av);
    }
    Q[n * HD + t] = aq;
    K[n * HD + t] = ak;
    V[n * HD + t] = av;
}

// ---------------- CSR build ----------------
__global__ void zero_kernel(int* __restrict__ p, int n)
{
    const int i = blockIdx.x * blockDim.x + threadIdx.x;
    if (i < n) p[i] = 0;
}

__global__ void count_kernel(const int* __restrict__ ei, int* __restrict__ count, int Ne)
{
    const int e = blockIdx.x * blockDim.x + threadIdx.x;
    if (e < Ne) atomicAdd(&count[ei[Ne + e]], 1);
}

__global__ void __launch_bounds__(1024) scan_kernel(
    const int* __restrict__ count, int* __restrict__ off, int* __restrict__ cursor, int N)
{
    __shared__ int buf[1024];
    __shared__ int stot;
    const int t = threadIdx.x;
    if (t == 0) stot = 0;
    __syncthreads();
    for (int base = 0; base < N; base += 1024) {
        const int v = (base + t < N) ? count[base + t] : 0;
        buf[t] = v;
        __syncthreads();
        for (int s = 1; s < 1024; s <<= 1) {
            const int add = (t >= s) ? buf[t - s] : 0;
            __syncthreads();
            buf[t] += add;
            __syncthreads();
        }
        const int excl = buf[t] - v;
        if (base + t < N) {
            off[base + t]    = stot + excl;
            cursor[base + t] = stot + excl;
        }
        __syncthreads();
        if (t == 1023) stot += buf[1023];
        __syncthreads();
    }
}

__global__ void scatter_kernel(const int* __restrict__ ei, int* __restrict__ cursor,
                               int* __restrict__ elist, int Ne)
{
    const int e = blockIdx.x * blockDim.x + threadIdx.x;
    if (e < Ne) {
        const int dst = ei[Ne + e];
        const int pos = atomicAdd(&cursor[dst], 1);
        elist[pos] = e;
    }
}

// ---------------- Edge pass: fused E-GEMM + score + oE + ea ----------------
// Block = 128 threads (one per (h,d) score element), ECHUNK edges per block.
__global__ void __launch_bounds__(128) edge_kernel(
    const float* __restrict__ edge_attr, const int* __restrict__ ei,
    const float* __restrict__ Ew, const float* __restrict__ Eb,
    const float* __restrict__ Aw,
    const float* __restrict__ Q, const float* __restrict__ K,
    float* __restrict__ oE, float* __restrict__ ea_ws, int Ne)
{
    const int t = threadIdx.x;          // 0..127
    const int h = t >> 4, d = t & 15;
    const int c1 = h * (2 * D) + d;     // Ex1 column in E-row (256 wide)
    const int c2 = c1 + D;              // Ex2 column

    __shared__ float xs[ECHUNK][IN_DIM];
    const long e0 = (long)blockIdx.x * ECHUNK;

    for (int i = t; i < ECHUNK * IN_DIM; i += 128) {
        const long gi = e0 * IN_DIM + i;
        xs[i >> 6][i & 63] = (gi < (long)Ne * IN_DIM) ? edge_attr[gi] : 0.0f;
    }
    __syncthreads();

    const float b1 = Eb[c1], b2 = Eb[c2];
    float acc1[ECHUNK], acc2[ECHUNK];
#pragma unroll
    for (int e = 0; e < ECHUNK; ++e) { acc1[e] = b1; acc2[e] = b2; }

#pragma unroll 4
    for (int k = 0; k < IN_DIM; ++k) {
        const float w1 = Ew[k * (2 * H * D) + c1];
        const float w2 = Ew[k * (2 * H * D) + c2];
#pragma unroll
        for (int e = 0; e < ECHUNK; ++e) {
            const float xv = xs[e][k];
            acc1[e] = fmaf(xv, w1, acc1[e]);
            acc2[e] = fmaf(xv, w2, acc2[e]);
        }
    }

    const float aw = Aw[d * H + h];     // Aw is (D,H,1)
#pragma unroll
    for (int e = 0; e < ECHUNK; ++e) {
        const int eid = (int)e0 + e;
        if (eid >= Ne) break;
        const int src = ei[eid];
        const int dst = ei[Ne + eid];
        const float s2 = acc1[e] * acc2[e];
        const float ss = copysignf(sqrtf(fabsf(s2)), s2);   // sqrt(relu(s2)) - sqrt(relu(-s2))
        const float score = K[src * HD + t] + Q[dst * HD + t] + ss;
        oE[(long)eid * HD + t] = score;

        // a[e,h] = sum_d score[h,d] * Aw[d,h]; reduce over 16-lane group
        float v = score * aw;
        v += __shfl_xor(v, 1);
        v += __shfl_xor(v, 2);
        v += __shfl_xor(v, 4);
        v += __shfl_xor(v, 8);
        if (d == 0) {
            const float a = fminf(fmaxf(v, -CLAMP_V), CLAMP_V);
            // shift-invariant softmax: use fixed shift CLAMP_V (a-5 in [-10,0])
            ea_ws[(long)eid * H + h] = __expf(a - CLAMP_V);
        }
    }
}

// ---------------- Node pass: CSR gather, normalize, VeRow einsum ----------------
__global__ void __launch_bounds__(128) node_kernel(
    const int* __restrict__ ei, const int* __restrict__ off, const int* __restrict__ count,
    const int* __restrict__ elist,
    const float* __restrict__ V, const float* __restrict__ oE, const float* __restrict__ ea_ws,
    const float* __restrict__ VeRow,
    float* __restrict__ nout, int Ne)
{
    const int n = blockIdx.x;
    const int t = threadIdx.x;          // (h,c) element of output
    const int h = t >> 4;
    const int o = off[n], cnt = count[n];

    float accV = 0.0f, accE = 0.0f, den = 0.0f;
    for (int i = 0; i < cnt; ++i) {
        const int e = elist[o + i];
        const int src = ei[e];
        const float ea = ea_ws[(long)e * H + h];
        den += ea;
        accV = fmaf(ea, V[src * HD + t], accV);
        accE = fmaf(ea, oE[(long)e * HD + t], accE);
    }
    const float inv = 1.0f / (den + 1e-16f);
    accV *= inv;
    accE *= inv;

    __shared__ float sE[HD];
    sE[t] = accE;
    __syncthreads();

    float rowv = 0.0f;
    const int hb = h * D;
#pragma unroll
    for (int dp = 0; dp < D; ++dp)
        rowv = fmaf(sE[hb + dp], VeRow[dp * HD + t], rowv);

    nout[n * HD + t] = accV + rowv;
}

// ---------------- launch ----------------
extern "C" void kernel_launch(void* const* d_in, const int* in_sizes, int n_in,
                              void* d_out, int out_size, void* d_ws, size_t ws_size,
                              hipStream_t stream)
{
    const float* x         = (const float*)d_in[0];
    const float* edge_attr = (const float*)d_in[1];
    const int*   ei        = (const int*)d_in[2];
    const float* Qw = (const float*)d_in[3];
    const float* Qb = (const float*)d_in[4];
    const float* Kw = (const float*)d_in[5];
    const float* Kb = (const float*)d_in[6];
    const float* Ew = (const float*)d_in[7];
    const float* Eb = (const float*)d_in[8];
    const float* Vw = (const float*)d_in[9];
    const float* Vb = (const float*)d_in[10];
    const float* Aw = (const float*)d_in[11];
    const float* VeRow = (const float*)d_in[12];

    const int N  = in_sizes[0] / IN_DIM;
    const int Ne = in_sizes[2] / 2;

    char* ws = (char*)d_ws;
    float* Q      = (float*)ws; ws += (size_t)N * HD * 4;
    float* K      = (float*)ws; ws += (size_t)N * HD * 4;
    float* V      = (float*)ws; ws += (size_t)N * HD * 4;
    float* ea     = (float*)ws; ws += (size_t)Ne * H * 4;
    int*   count  = (int*)ws;   ws += (size_t)N * 4;
    int*   off    = (int*)ws;   ws += (size_t)N * 4;
    int*   cursor = (int*)ws;   ws += (size_t)N * 4;
    int*   elist  = (int*)ws;   ws += (size_t)Ne * 4;

    float* nout = (float*)d_out;
    float* oE   = nout + (size_t)N * HD;

    hipLaunchKernelGGL(qkv_kernel, dim3(N), dim3(128), 0, stream,
                       x, Qw, Qb, Kw, Kb, Vw, Vb, Q, K, V);
    hipLaunchKernelGGL(zero_kernel, dim3((N + 255) / 256), dim3(256), 0, stream, count, N);
    hipLaunchKernelGGL(count_kernel, dim3((Ne + 255) / 256), dim3(256), 0, stream, ei, count, Ne);
    hipLaunchKernelGGL(scan_kernel, dim3(1), dim3(1024), 0, stream, count, off, cursor, N);
    hipLaunchKernelGGL(scatter_kernel, dim3((Ne + 255) / 256), dim3(256), 0, stream,
                       ei, cursor, elist, Ne);
    hipLaunchKernelGGL(edge_kernel, dim3((Ne + ECHUNK - 1) / ECHUNK), dim3(128), 0, stream,
                       edge_attr, ei, Ew, Eb, Aw, Q, K, oE, ea, Ne);
    hipLaunchKernelGGL(node_kernel, dim3(N), dim3(128), 0, stream,
                       ei, off, count, elist, V, oE, ea, VeRow, nout, Ne);
}

// Round 4
// 581.991 us; speedup vs baseline: 1.1730x; 1.1730x over previous
//
#include <hip/hip_runtime.h>

#define IN_DIM 64
#define H 8
#define D 16
#define HD 128
#define CLAMP_V 5.0f
#define NCHUNK 8

typedef __attribute__((ext_vector_type(8))) short bf16x8;
typedef __attribute__((ext_vector_type(4))) float f32x4;

__device__ inline unsigned short f2b(float f) {
    unsigned int u = __float_as_uint(f);
    u += 0x7FFFu + ((u >> 16) & 1u);
    return (unsigned short)(u >> 16);
}
__device__ inline float b2f(unsigned short h) {
    return __uint_as_float((unsigned int)h << 16);
}
__device__ inline void split2(float f, unsigned short& hi, unsigned short& lo) {
    hi = f2b(f);
    lo = f2b(f - b2f(hi));
}

// ---------------- QKV projection: NCHUNK nodes per block ----------------
__global__ void __launch_bounds__(128) qkv_kernel(
    const float* __restrict__ x,
    const float* __restrict__ Qw, const float* __restrict__ Qb,
    const float* __restrict__ Kw, const float* __restrict__ Kb,
    const float* __restrict__ Vw, const float* __restrict__ Vb,
    float* __restrict__ Q, float* __restrict__ K, float* __restrict__ V)
{
    const int n0 = blockIdx.x * NCHUNK;
    const int t = threadIdx.x;
    __shared__ float xs[NCHUNK][IN_DIM];
    for (int i = t; i < NCHUNK * IN_DIM; i += 128)
        xs[i >> 6][i & 63] = x[(size_t)n0 * IN_DIM + i];
    __syncthreads();

    const float qb = Qb[t], kb = Kb[t], vb = Vb[t];
    float aq[NCHUNK], ak[NCHUNK], av[NCHUNK];
#pragma unroll
    for (int c = 0; c < NCHUNK; ++c) { aq[c] = qb; ak[c] = kb; av[c] = vb; }

#pragma unroll 4
    for (int k = 0; k < IN_DIM; ++k) {
        const float wq = Qw[k * HD + t];
        const float wk = Kw[k * HD + t];
        const float wv = Vw[k * HD + t];
#pragma unroll
        for (int c = 0; c < NCHUNK; ++c) {
            const float xv = xs[c][k];
            aq[c] = fmaf(xv, wq, aq[c]);
            ak[c] = fmaf(xv, wk, ak[c]);
            av[c] = fmaf(xv, wv, av[c]);
        }
    }
#pragma unroll
    for (int c = 0; c < NCHUNK; ++c) {
        Q[(size_t)(n0 + c) * HD + t] = aq[c];
        K[(size_t)(n0 + c) * HD + t] = ak[c];
        V[(size_t)(n0 + c) * HD + t] = av[c];
    }
}

// ---------------- prep: EwT bf16 hi/lo planes, each [256][64] ----------------
__global__ void prep_ewt_kernel(const float* __restrict__ Ew, unsigned short* __restrict__ EwT)
{
    const int idx = blockIdx.x * 256 + threadIdx.x;   // 16384 total
    const int k = idx >> 8, c = idx & 255;
    const float w = Ew[idx];
    unsigned short hi, lo;
    split2(w, hi, lo);
    EwT[c * 64 + k] = hi;
    EwT[16384 + c * 64 + k] = lo;
}

// ---------------- CSR build ----------------
__global__ void zero_kernel(int* __restrict__ p, int n)
{
    const int i = blockIdx.x * blockDim.x + threadIdx.x;
    if (i < n) p[i] = 0;
}

__global__ void count_kernel(const int* __restrict__ ei, int* __restrict__ count, int Ne)
{
    const int e = blockIdx.x * blockDim.x + threadIdx.x;
    if (e < Ne) atomicAdd(&count[ei[Ne + e]], 1);
}

__global__ void __launch_bounds__(512) scan_block_kernel(
    const int* __restrict__ count, int* __restrict__ off_part, int* __restrict__ bsum, int N)
{
    __shared__ int buf[512];
    const int t = threadIdx.x;
    const int g = blockIdx.x * 512 + t;
    const int v = (g < N) ? count[g] : 0;
    buf[t] = v;
    __syncthreads();
    for (int s = 1; s < 512; s <<= 1) {
        const int add = (t >= s) ? buf[t - s] : 0;
        __syncthreads();
        buf[t] += add;
        __syncthreads();
    }
    if (g < N) off_part[g] = buf[t] - v;
    if (t == 511) bsum[blockIdx.x] = buf[511];
}

__global__ void __launch_bounds__(64) scan_tops_kernel(int* __restrict__ bsum, int NB)
{
    const int t = threadIdx.x;
    int v = (t < NB) ? bsum[t] : 0;
    const int orig = v;
#pragma unroll
    for (int s = 1; s < 64; s <<= 1) {
        const int o = __shfl_up(v, s);
        if (t >= s) v += o;
    }
    if (t < NB) bsum[t] = v - orig;   // exclusive
}

__global__ void __launch_bounds__(512) scan_add_kernel(
    const int* __restrict__ off_part, const int* __restrict__ bsum,
    int* __restrict__ off, int* __restrict__ cursor, int N)
{
    const int g = blockIdx.x * 512 + threadIdx.x;
    if (g < N) {
        const int o = off_part[g] + bsum[g >> 9];
        off[g] = o;
        cursor[g] = o;
    }
}

__global__ void scatter_kernel(const int* __restrict__ ei, int* __restrict__ cursor,
                               int* __restrict__ elist, int Ne)
{
    const int e = blockIdx.x * blockDim.x + threadIdx.x;
    if (e < Ne) {
        const int dst = ei[Ne + e];
        const int pos = atomicAdd(&cursor[dst], 1);
        elist[pos] = e;
    }
}

// ---------------- Edge pass: split-bf16 MFMA E-GEMM + score + oE + ea ----------
// Block = 256 threads (4 waves), 64 edges/block (16 per wave). No LDS.
// 3-term split GEMM: a_hi*w_hi + a_lo*w_hi + a_hi*w_lo  (fp32-grade precision).
__global__ void __launch_bounds__(256) edge_kernel(
    const float* __restrict__ edge_attr, const int* __restrict__ ei,
    const unsigned short* __restrict__ EwTg,
    const float* __restrict__ Eb, const float* __restrict__ Aw,
    const float* __restrict__ Q, const float* __restrict__ K,
    float* __restrict__ oE, float* __restrict__ ea_ws, int Ne)
{
    const int t = threadIdx.x;
    const int e0 = blockIdx.x * 64;
    const int lane = t & 63, wid = t >> 6;
    const int m = lane & 15, q = lane >> 4;
    const int d = m;

    // edge indices for this lane's 4 output rows
    int sld[4], dld[4];
#pragma unroll
    for (int j = 0; j < 4; ++j) {
        const int el = wid * 16 + q * 4 + j;
        sld[j] = ei[e0 + el];
        dld[j] = ei[Ne + e0 + el];
    }

    // A fragments: edge row = wid*16 + m, k = q*8..q*8+7 (+32 for kstep 1)
    const float* ar = edge_attr + (size_t)(e0 + wid * 16 + m) * 64 + q * 8;
    float av[16];
    *(float4*)(av)      = *(const float4*)(ar);
    *(float4*)(av + 4)  = *(const float4*)(ar + 4);
    *(float4*)(av + 8)  = *(const float4*)(ar + 32);
    *(float4*)(av + 12) = *(const float4*)(ar + 36);
    bf16x8 a0h, a0l, a1h, a1l;
#pragma unroll
    for (int i = 0; i < 8; ++i) {
        unsigned short hi, lo;
        split2(av[i], hi, lo);     a0h[i] = (short)hi; a0l[i] = (short)lo;
        split2(av[i + 8], hi, lo); a1h[i] = (short)hi; a1l[i] = (short)lo;
    }

#pragma unroll 2
    for (int h = 0; h < 8; ++h) {
        const int c1 = h * 32 + d;        // Ex1 column
        const int c2 = c1 + 16;           // Ex2 column
        const unsigned short* b1p = EwTg + c1 * 64 + q * 8;
        const unsigned short* b2p = EwTg + c2 * 64 + q * 8;
        const bf16x8 b00h = *(const bf16x8*)(b1p);
        const bf16x8 b01h = *(const bf16x8*)(b1p + 32);
        const bf16x8 b00l = *(const bf16x8*)(b1p + 16384);
        const bf16x8 b01l = *(const bf16x8*)(b1p + 16384 + 32);
        const bf16x8 b10h = *(const bf16x8*)(b2p);
        const bf16x8 b11h = *(const bf16x8*)(b2p + 32);
        const bf16x8 b10l = *(const bf16x8*)(b2p + 16384);
        const bf16x8 b11l = *(const bf16x8*)(b2p + 16384 + 32);

        f32x4 acc1 = {0.f, 0.f, 0.f, 0.f}, acc2 = {0.f, 0.f, 0.f, 0.f};
        acc1 = __builtin_amdgcn_mfma_f32_16x16x32_bf16(a0h, b00h, acc1, 0, 0, 0);
        acc1 = __builtin_amdgcn_mfma_f32_16x16x32_bf16(a1h, b01h, acc1, 0, 0, 0);
        acc1 = __builtin_amdgcn_mfma_f32_16x16x32_bf16(a0l, b00h, acc1, 0, 0, 0);
        acc1 = __builtin_amdgcn_mfma_f32_16x16x32_bf16(a1l, b01h, acc1, 0, 0, 0);
        acc1 = __builtin_amdgcn_mfma_f32_16x16x32_bf16(a0h, b00l, acc1, 0, 0, 0);
        acc1 = __builtin_amdgcn_mfma_f32_16x16x32_bf16(a1h, b01l, acc1, 0, 0, 0);
        acc2 = __builtin_amdgcn_mfma_f32_16x16x32_bf16(a0h, b10h, acc2, 0, 0, 0);
        acc2 = __builtin_amdgcn_mfma_f32_16x16x32_bf16(a1h, b11h, acc2, 0, 0, 0);
        acc2 = __builtin_amdgcn_mfma_f32_16x16x32_bf16(a0l, b10h, acc2, 0, 0, 0);
        acc2 = __builtin_amdgcn_mfma_f32_16x16x32_bf16(a1l, b11h, acc2, 0, 0, 0);
        acc2 = __builtin_amdgcn_mfma_f32_16x16x32_bf16(a0h, b10l, acc2, 0, 0, 0);
        acc2 = __builtin_amdgcn_mfma_f32_16x16x32_bf16(a1h, b11l, acc2, 0, 0, 0);

        const float eb1 = Eb[c1], eb2 = Eb[c2];
        const float aw = Aw[d * H + h];
        float eav[4];
#pragma unroll
        for (int j = 0; j < 4; ++j) {
            const int el = wid * 16 + q * 4 + j;          // edge row = 4q+j within wave tile
            const float x1 = acc1[j] + eb1;
            const float x2 = acc2[j] + eb2;
            const float s2 = x1 * x2;
            const float ss = copysignf(sqrtf(fabsf(s2)), s2);
            const float sc = K[(size_t)sld[j] * HD + h * D + d]
                           + Q[(size_t)dld[j] * HD + h * D + d] + ss;
            oE[(size_t)(e0 + el) * HD + h * D + d] = sc;
            float v = sc * aw;
            v += __shfl_xor(v, 1);
            v += __shfl_xor(v, 2);
            v += __shfl_xor(v, 4);
            v += __shfl_xor(v, 8);
            eav[j] = v;
        }
        if (d == 0) {
#pragma unroll
            for (int j = 0; j < 4; ++j) {
                const int el = wid * 16 + q * 4 + j;
                const float a = fminf(fmaxf(eav[j], -CLAMP_V), CLAMP_V);
                ea_ws[(size_t)(e0 + el) * H + h] = __expf(a - CLAMP_V);
            }
        }
    }
}

// ---------------- Node pass: CSR gather, normalize, VeRow einsum ----------------
__global__ void __launch_bounds__(128) node_kernel(
    const int* __restrict__ ei, const int* __restrict__ off, const int* __restrict__ count,
    const int* __restrict__ elist,
    const float* __restrict__ V, const float* __restrict__ oE, const float* __restrict__ ea_ws,
    const float* __restrict__ VeRow,
    float* __restrict__ nout, int Ne)
{
    const int n = blockIdx.x;
    const int t = threadIdx.x;
    const int h = t >> 4;
    const int o = off[n], cnt = count[n];

    float accV = 0.0f, accE = 0.0f, den = 0.0f;
    int e_n = 0, s_n = 0;
    if (cnt > 0) { e_n = elist[o]; s_n = ei[e_n]; }
    for (int i = 0; i < cnt; ++i) {
        const int e = e_n, s = s_n;
        if (i + 1 < cnt) { e_n = elist[o + i + 1]; s_n = ei[e_n]; }
        const float w = ea_ws[(size_t)e * H + h];
        den += w;
        accV = fmaf(w, V[(size_t)s * HD + t], accV);
        accE = fmaf(w, oE[(size_t)e * HD + t], accE);
    }
    const float inv = 1.0f / (den + 1e-16f);
    accV *= inv;
    accE *= inv;

    __shared__ float sE[HD];
    sE[t] = accE;
    __syncthreads();

    float rowv = 0.0f;
    const int hb = h * D;
#pragma unroll
    for (int dp = 0; dp < D; ++dp)
        rowv = fmaf(sE[hb + dp], VeRow[dp * HD + t], rowv);

    nout[n * HD + t] = accV + rowv;
}

// ---------------- launch ----------------
extern "C" void kernel_launch(void* const* d_in, const int* in_sizes, int n_in,
                              void* d_out, int out_size, void* d_ws, size_t ws_size,
                              hipStream_t stream)
{
    const float* x         = (const float*)d_in[0];
    const float* edge_attr = (const float*)d_in[1];
    const int*   ei        = (const int*)d_in[2];
    const float* Qw = (const float*)d_in[3];
    const float* Qb = (const float*)d_in[4];
    const float* Kw = (const float*)d_in[5];
    const float* Kb = (const float*)d_in[6];
    const float* Ew = (const float*)d_in[7];
    const float* Eb = (const float*)d_in[8];
    const float* Vw = (const float*)d_in[9];
    const float* Vb = (const float*)d_in[10];
    const float* Aw = (const float*)d_in[11];
    const float* VeRow = (const float*)d_in[12];

    const int N  = in_sizes[0] / IN_DIM;
    const int Ne = in_sizes[2] / 2;
    const int NB = (N + 511) / 512;

    char* ws = (char*)d_ws;
    float* Q       = (float*)ws; ws += (size_t)N * HD * 4;
    float* K       = (float*)ws; ws += (size_t)N * HD * 4;
    float* V       = (float*)ws; ws += (size_t)N * HD * 4;
    float* ea      = (float*)ws; ws += (size_t)Ne * H * 4;
    int*   count   = (int*)ws;   ws += (size_t)N * 4;
    int*   off     = (int*)ws;   ws += (size_t)N * 4;
    int*   cursor  = (int*)ws;   ws += (size_t)N * 4;
    int*   offp    = (int*)ws;   ws += (size_t)N * 4;
    int*   elist   = (int*)ws;   ws += (size_t)Ne * 4;
    int*   bsum    = (int*)ws;   ws += 256;
    unsigned short* EwT = (unsigned short*)ws; ws += 2 * 16384 * 2;

    float* nout = (float*)d_out;
    float* oE   = nout + (size_t)N * HD;

    hipLaunchKernelGGL(prep_ewt_kernel, dim3(64), dim3(256), 0, stream, Ew, EwT);
    hipLaunchKernelGGL(qkv_kernel, dim3(N / NCHUNK), dim3(128), 0, stream,
                       x, Qw, Qb, Kw, Kb, Vw, Vb, Q, K, V);
    hipLaunchKernelGGL(zero_kernel, dim3((N + 255) / 256), dim3(256), 0, stream, count, N);
    hipLaunchKernelGGL(count_kernel, dim3((Ne + 255) / 256), dim3(256), 0, stream, ei, count, Ne);
    hipLaunchKernelGGL(scan_block_kernel, dim3(NB), dim3(512), 0, stream, count, offp, bsum, N);
    hipLaunchKernelGGL(scan_tops_kernel, dim3(1), dim3(64), 0, stream, bsum, NB);
    hipLaunchKernelGGL(scan_add_kernel, dim3(NB), dim3(512), 0, stream, offp, bsum, off, cursor, N);
    hipLaunchKernelGGL(scatter_kernel, dim3((Ne + 255) / 256), dim3(256), 0, stream,
                       ei, cursor, elist, Ne);
    hipLaunchKernelGGL(edge_kernel, dim3(Ne / 64), dim3(256), 0, stream,
                       edge_attr, ei, EwT, Eb, Aw, Q, K, oE, ea, Ne);
    hipLaunchKernelGGL(node_kernel, dim3(N), dim3(128), 0, stream,
                       ei, off, count, elist, V, oE, ea, VeRow, nout, Ne);
}

// Round 5
// 554.284 us; speedup vs baseline: 1.2316x; 1.0500x over previous
//
#include <hip/hip_runtime.h>

#define IN_DIM 64
#define H 8
#define D 16
#define HD 128
#define CLAMP_V 5.0f
#define NCHUNK 8

typedef __attribute__((ext_vector_type(8))) short bf16x8;
typedef __attribute__((ext_vector_type(4))) float f32x4;

__device__ inline unsigned short f2b(float f) {
    unsigned int u = __float_as_uint(f);
    u += 0x7FFFu + ((u >> 16) & 1u);
    return (unsigned short)(u >> 16);
}
__device__ inline float b2f(unsigned short h) {
    return __uint_as_float((unsigned int)h << 16);
}
__device__ inline void split2(float f, unsigned short& hi, unsigned short& lo) {
    hi = f2b(f);
    lo = f2b(f - b2f(hi));
}

// ---------------- QKV projection: NCHUNK nodes per block ----------------
__global__ void __launch_bounds__(128) qkv_kernel(
    const float* __restrict__ x,
    const float* __restrict__ Qw, const float* __restrict__ Qb,
    const float* __restrict__ Kw, const float* __restrict__ Kb,
    const float* __restrict__ Vw, const float* __restrict__ Vb,
    float* __restrict__ Q, float* __restrict__ K, float* __restrict__ V)
{
    const int n0 = blockIdx.x * NCHUNK;
    const int t = threadIdx.x;
    __shared__ float xs[NCHUNK][IN_DIM];
    for (int i = t; i < NCHUNK * IN_DIM; i += 128)
        xs[i >> 6][i & 63] = x[(size_t)n0 * IN_DIM + i];
    __syncthreads();

    const float qb = Qb[t], kb = Kb[t], vb = Vb[t];
    float aq[NCHUNK], ak[NCHUNK], av[NCHUNK];
#pragma unroll
    for (int c = 0; c < NCHUNK; ++c) { aq[c] = qb; ak[c] = kb; av[c] = vb; }

#pragma unroll 4
    for (int k = 0; k < IN_DIM; ++k) {
        const float wq = Qw[k * HD + t];
        const float wk = Kw[k * HD + t];
        const float wv = Vw[k * HD + t];
#pragma unroll
        for (int c = 0; c < NCHUNK; ++c) {
            const float xv = xs[c][k];
            aq[c] = fmaf(xv, wq, aq[c]);
            ak[c] = fmaf(xv, wk, ak[c]);
            av[c] = fmaf(xv, wv, av[c]);
        }
    }
#pragma unroll
    for (int c = 0; c < NCHUNK; ++c) {
        Q[(size_t)(n0 + c) * HD + t] = aq[c];
        K[(size_t)(n0 + c) * HD + t] = ak[c];
        V[(size_t)(n0 + c) * HD + t] = av[c];
    }
}

// ---------------- prep: EwT bf16 hi/lo planes, each [256][64] ----------------
__global__ void prep_ewt_kernel(const float* __restrict__ Ew, unsigned short* __restrict__ EwT)
{
    const int idx = blockIdx.x * 256 + threadIdx.x;   // 16384 total
    const int k = idx >> 8, c = idx & 255;
    const float w = Ew[idx];
    unsigned short hi, lo;
    split2(w, hi, lo);
    EwT[c * 64 + k] = hi;
    EwT[16384 + c * 64 + k] = lo;
}

// ---------------- CSR build ----------------
__global__ void zero_kernel(int* __restrict__ p, int n)
{
    const int i = blockIdx.x * blockDim.x + threadIdx.x;
    if (i < n) p[i] = 0;
}

__global__ void count_kernel(const int* __restrict__ ei, int* __restrict__ count, int Ne)
{
    const int e = blockIdx.x * blockDim.x + threadIdx.x;
    if (e < Ne) atomicAdd(&count[ei[Ne + e]], 1);
}

__global__ void __launch_bounds__(512) scan_block_kernel(
    const int* __restrict__ count, int* __restrict__ off_part, int* __restrict__ bsum, int N)
{
    __shared__ int buf[512];
    const int t = threadIdx.x;
    const int g = blockIdx.x * 512 + t;
    const int v = (g < N) ? count[g] : 0;
    buf[t] = v;
    __syncthreads();
    for (int s = 1; s < 512; s <<= 1) {
        const int add = (t >= s) ? buf[t - s] : 0;
        __syncthreads();
        buf[t] += add;
        __syncthreads();
    }
    if (g < N) off_part[g] = buf[t] - v;
    if (t == 511) bsum[blockIdx.x] = buf[511];
}

__global__ void __launch_bounds__(64) scan_tops_kernel(int* __restrict__ bsum, int NB)
{
    const int t = threadIdx.x;
    int v = (t < NB) ? bsum[t] : 0;
    const int orig = v;
#pragma unroll
    for (int s = 1; s < 64; s <<= 1) {
        const int o = __shfl_up(v, s);
        if (t >= s) v += o;
    }
    if (t < NB) bsum[t] = v - orig;   // exclusive
}

__global__ void __launch_bounds__(512) scan_add_kernel(
    const int* __restrict__ off_part, const int* __restrict__ bsum,
    int* __restrict__ off, int* __restrict__ cursor, int N)
{
    const int g = blockIdx.x * 512 + threadIdx.x;
    if (g < N) {
        const int o = off_part[g] + bsum[g >> 9];
        off[g] = o;
        cursor[g] = o;
    }
}

__global__ void scatter_kernel(const int* __restrict__ ei, int* __restrict__ cursor,
                               int* __restrict__ elist, int Ne)
{
    const int e = blockIdx.x * blockDim.x + threadIdx.x;
    if (e < Ne) {
        const int dst = ei[Ne + e];
        const int pos = atomicAdd(&cursor[dst], 1);
        elist[pos] = e;
    }
}

// ---------------- Edge pass: split-bf16 MFMA E-GEMM + score + oE + ea ----------
// Block = 256 threads (4 waves), 64 edges/block. All K/Q gathers hoisted before
// the head loop (64 loads in flight); oE staged in LDS, written coalesced.
#define LSTR 132
__global__ void __launch_bounds__(256) edge_kernel(
    const float* __restrict__ edge_attr, const int* __restrict__ ei,
    const unsigned short* __restrict__ EwTg,
    const float* __restrict__ Eb, const float* __restrict__ Aw,
    const float* __restrict__ Q, const float* __restrict__ K,
    float* __restrict__ oE, float* __restrict__ ea_ws, int Ne)
{
    __shared__ float soe[64 * LSTR];
    const int t = threadIdx.x;
    const int e0 = blockIdx.x * 64;
    const int lane = t & 63, wid = t >> 6;
    const int m = lane & 15, q = lane >> 4;   // m = d

    // edge indices for this lane's 4 output rows
    int sld[4], dld[4];
#pragma unroll
    for (int j = 0; j < 4; ++j) {
        const int el = wid * 16 + q * 4 + j;
        sld[j] = ei[e0 + el];
        dld[j] = ei[Ne + e0 + el];
    }

    // A fragments: edge row = wid*16 + m, k = q*8..q*8+7 (+32 for kstep 1)
    const float* ar = edge_attr + (size_t)(e0 + wid * 16 + m) * 64 + q * 8;
    float av[16];
    *(float4*)(av)      = *(const float4*)(ar);
    *(float4*)(av + 4)  = *(const float4*)(ar + 4);
    *(float4*)(av + 8)  = *(const float4*)(ar + 32);
    *(float4*)(av + 12) = *(const float4*)(ar + 36);

    // hoist ALL K/Q gathers (issue 64 independent loads up-front)
    float kk[8][4], qq[8][4];
#pragma unroll
    for (int h = 0; h < 8; ++h)
#pragma unroll
        for (int j = 0; j < 4; ++j) {
            kk[h][j] = K[(size_t)sld[j] * HD + h * D + m];
            qq[h][j] = Q[(size_t)dld[j] * HD + h * D + m];
        }

    bf16x8 a0h, a0l, a1h, a1l;
#pragma unroll
    for (int i = 0; i < 8; ++i) {
        unsigned short hi, lo;
        split2(av[i], hi, lo);     a0h[i] = (short)hi; a0l[i] = (short)lo;
        split2(av[i + 8], hi, lo); a1h[i] = (short)hi; a1l[i] = (short)lo;
    }

#pragma unroll
    for (int h = 0; h < 8; ++h) {
        const int c1 = h * 32 + m;        // Ex1 column
        const int c2 = c1 + 16;           // Ex2 column
        const unsigned short* b1p = EwTg + c1 * 64 + q * 8;
        const unsigned short* b2p = EwTg + c2 * 64 + q * 8;
        const bf16x8 b00h = *(const bf16x8*)(b1p);
        const bf16x8 b01h = *(const bf16x8*)(b1p + 32);
        const bf16x8 b00l = *(const bf16x8*)(b1p + 16384);
        const bf16x8 b01l = *(const bf16x8*)(b1p + 16384 + 32);
        const bf16x8 b10h = *(const bf16x8*)(b2p);
        const bf16x8 b11h = *(const bf16x8*)(b2p + 32);
        const bf16x8 b10l = *(const bf16x8*)(b2p + 16384);
        const bf16x8 b11l = *(const bf16x8*)(b2p + 16384 + 32);

        f32x4 acc1 = {0.f, 0.f, 0.f, 0.f}, acc2 = {0.f, 0.f, 0.f, 0.f};
        acc1 = __builtin_amdgcn_mfma_f32_16x16x32_bf16(a0h, b00h, acc1, 0, 0, 0);
        acc1 = __builtin_amdgcn_mfma_f32_16x16x32_bf16(a1h, b01h, acc1, 0, 0, 0);
        acc1 = __builtin_amdgcn_mfma_f32_16x16x32_bf16(a0l, b00h, acc1, 0, 0, 0);
        acc1 = __builtin_amdgcn_mfma_f32_16x16x32_bf16(a1l, b01h, acc1, 0, 0, 0);
        acc1 = __builtin_amdgcn_mfma_f32_16x16x32_bf16(a0h, b00l, acc1, 0, 0, 0);
        acc1 = __builtin_amdgcn_mfma_f32_16x16x32_bf16(a1h, b01l, acc1, 0, 0, 0);
        acc2 = __builtin_amdgcn_mfma_f32_16x16x32_bf16(a0h, b10h, acc2, 0, 0, 0);
        acc2 = __builtin_amdgcn_mfma_f32_16x16x32_bf16(a1h, b11h, acc2, 0, 0, 0);
        acc2 = __builtin_amdgcn_mfma_f32_16x16x32_bf16(a0l, b10h, acc2, 0, 0, 0);
        acc2 = __builtin_amdgcn_mfma_f32_16x16x32_bf16(a1l, b11h, acc2, 0, 0, 0);
        acc2 = __builtin_amdgcn_mfma_f32_16x16x32_bf16(a0h, b10l, acc2, 0, 0, 0);
        acc2 = __builtin_amdgcn_mfma_f32_16x16x32_bf16(a1h, b11l, acc2, 0, 0, 0);

        const float eb1 = Eb[c1], eb2 = Eb[c2];
        const float aw = Aw[m * H + h];
        float eav[4];
#pragma unroll
        for (int j = 0; j < 4; ++j) {
            const int el = wid * 16 + q * 4 + j;
            const float x1 = acc1[j] + eb1;
            const float x2 = acc2[j] + eb2;
            const float s2 = x1 * x2;
            const float ss = copysignf(sqrtf(fabsf(s2)), s2);
            const float sc = kk[h][j] + qq[h][j] + ss;
            soe[el * LSTR + h * D + m] = sc;
            float v = sc * aw;
            v += __shfl_xor(v, 1);
            v += __shfl_xor(v, 2);
            v += __shfl_xor(v, 4);
            v += __shfl_xor(v, 8);
            eav[j] = v;
        }
        if (m == 0) {
#pragma unroll
            for (int j = 0; j < 4; ++j) {
                const int el = wid * 16 + q * 4 + j;
                const float a = fminf(fmaxf(eav[j], -CLAMP_V), CLAMP_V);
                ea_ws[(size_t)(e0 + el) * H + h] = __expf(a - CLAMP_V);
            }
        }
    }

    __syncthreads();
    // coalesced writeout: 64 rows x 128 floats = one contiguous 32 KB span
    float4* dst = (float4*)(oE + (size_t)e0 * HD);
#pragma unroll
    for (int u0 = 0; u0 < 2048; u0 += 256) {
        const int u = u0 + t;
        const int el = u >> 5, c4 = u & 31;
        dst[u] = *(float4*)&soe[el * LSTR + c4 * 4];
    }
}

// ---------------- Node pass: CSR gather (4-deep pipeline), normalize, einsum ---
__global__ void __launch_bounds__(128) node_kernel(
    const int* __restrict__ ei, const int* __restrict__ off, const int* __restrict__ count,
    const int* __restrict__ elist,
    const float* __restrict__ V, const float* __restrict__ oE, const float* __restrict__ ea_ws,
    const float* __restrict__ VeRow,
    float* __restrict__ nout, int Ne)
{
    const int n = blockIdx.x;
    const int t = threadIdx.x;
    const int h = t >> 4;
    const int o = off[n], cnt = count[n];

    float accV = 0.0f, accE = 0.0f, den = 0.0f;
    int i = 0;
    for (; i + 4 <= cnt; i += 4) {
        const int e0_ = elist[o + i],     e1_ = elist[o + i + 1];
        const int e2_ = elist[o + i + 2], e3_ = elist[o + i + 3];
        const int s0_ = ei[e0_], s1_ = ei[e1_], s2_ = ei[e2_], s3_ = ei[e3_];
        const float w0 = ea_ws[(size_t)e0_ * H + h];
        const float w1 = ea_ws[(size_t)e1_ * H + h];
        const float w2 = ea_ws[(size_t)e2_ * H + h];
        const float w3 = ea_ws[(size_t)e3_ * H + h];
        const float v0 = V[(size_t)s0_ * HD + t];
        const float v1 = V[(size_t)s1_ * HD + t];
        const float v2 = V[(size_t)s2_ * HD + t];
        const float v3 = V[(size_t)s3_ * HD + t];
        const float p0 = oE[(size_t)e0_ * HD + t];
        const float p1 = oE[(size_t)e1_ * HD + t];
        const float p2 = oE[(size_t)e2_ * HD + t];
        const float p3 = oE[(size_t)e3_ * HD + t];
        den += (w0 + w1) + (w2 + w3);
        accV = fmaf(w0, v0, accV); accV = fmaf(w1, v1, accV);
        accV = fmaf(w2, v2, accV); accV = fmaf(w3, v3, accV);
        accE = fmaf(w0, p0, accE); accE = fmaf(w1, p1, accE);
        accE = fmaf(w2, p2, accE); accE = fmaf(w3, p3, accE);
    }
    for (; i < cnt; ++i) {
        const int e = elist[o + i];
        const int s = ei[e];
        const float w = ea_ws[(size_t)e * H + h];
        den += w;
        accV = fmaf(w, V[(size_t)s * HD + t], accV);
        accE = fmaf(w, oE[(size_t)e * HD + t], accE);
    }
    const float inv = 1.0f / (den + 1e-16f);
    accV *= inv;
    accE *= inv;

    __shared__ float sE[HD];
    sE[t] = accE;
    __syncthreads();

    float rowv = 0.0f;
    const int hb = h * D;
#pragma unroll
    for (int dp = 0; dp < D; ++dp)
        rowv = fmaf(sE[hb + dp], VeRow[dp * HD + t], rowv);

    nout[n * HD + t] = accV + rowv;
}

// ---------------- launch ----------------
extern "C" void kernel_launch(void* const* d_in, const int* in_sizes, int n_in,
                              void* d_out, int out_size, void* d_ws, size_t ws_size,
                              hipStream_t stream)
{
    const float* x         = (const float*)d_in[0];
    const float* edge_attr = (const float*)d_in[1];
    const int*   ei        = (const int*)d_in[2];
    const float* Qw = (const float*)d_in[3];
    const float* Qb = (const float*)d_in[4];
    const float* Kw = (const float*)d_in[5];
    const float* Kb = (const float*)d_in[6];
    const float* Ew = (const float*)d_in[7];
    const float* Eb = (const float*)d_in[8];
    const float* Vw = (const float*)d_in[9];
    const float* Vb = (const float*)d_in[10];
    const float* Aw = (const float*)d_in[11];
    const float* VeRow = (const float*)d_in[12];

    const int N  = in_sizes[0] / IN_DIM;
    const int Ne = in_sizes[2] / 2;
    const int NB = (N + 511) / 512;

    char* ws = (char*)d_ws;
    float* Q       = (float*)ws; ws += (size_t)N * HD * 4;
    float* K       = (float*)ws; ws += (size_t)N * HD * 4;
    float* V       = (float*)ws; ws += (size_t)N * HD * 4;
    float* ea      = (float*)ws; ws += (size_t)Ne * H * 4;
    int*   count   = (int*)ws;   ws += (size_t)N * 4;
    int*   off     = (int*)ws;   ws += (size_t)N * 4;
    int*   cursor  = (int*)ws;   ws += (size_t)N * 4;
    int*   offp    = (int*)ws;   ws += (size_t)N * 4;
    int*   elist   = (int*)ws;   ws += (size_t)Ne * 4;
    int*   bsum    = (int*)ws;   ws += 256;
    unsigned short* EwT = (unsigned short*)ws; ws += 2 * 16384 * 2;

    float* nout = (float*)d_out;
    float* oE   = nout + (size_t)N * HD;

    hipLaunchKernelGGL(prep_ewt_kernel, dim3(64), dim3(256), 0, stream, Ew, EwT);
    hipLaunchKernelGGL(qkv_kernel, dim3(N / NCHUNK), dim3(128), 0, stream,
                       x, Qw, Qb, Kw, Kb, Vw, Vb, Q, K, V);
    hipLaunchKernelGGL(zero_kernel, dim3((N + 255) / 256), dim3(256), 0, stream, count, N);
    hipLaunchKernelGGL(count_kernel, dim3((Ne + 255) / 256), dim3(256), 0, stream, ei, count, Ne);
    hipLaunchKernelGGL(scan_block_kernel, dim3(NB), dim3(512), 0, stream, count, offp, bsum, N);
    hipLaunchKernelGGL(scan_tops_kernel, dim3(1), dim3(64), 0, stream, bsum, NB);
    hipLaunchKernelGGL(scan_add_kernel, dim3(NB), dim3(512), 0, stream, offp, bsum, off, cursor, N);
    hipLaunchKernelGGL(scatter_kernel, dim3((Ne + 255) / 256), dim3(256), 0, stream,
                       ei, cursor, elist, Ne);
    hipLaunchKernelGGL(edge_kernel, dim3(Ne / 64), dim3(256), 0, stream,
                       edge_attr, ei, EwT, Eb, Aw, Q, K, oE, ea, Ne);
    hipLaunchKernelGGL(node_kernel, dim3(N), dim3(128), 0, stream,
                       ei, off, count, elist, V, oE, ea, VeRow, nout, Ne);
}